// Round 1
// baseline (445.595 us; speedup 1.0000x reference)
//
#include <hip/hip_runtime.h>
#include <hip/hip_bf16.h>

typedef __attribute__((ext_vector_type(4))) float f32x4;
typedef __attribute__((ext_vector_type(8))) short short8;

#define HH 512
#define BB 32
#define SS 2048
#define KK 1024  // 2H

__device__ __forceinline__ unsigned short f2bf(float f) {
    unsigned int u = __float_as_uint(f);
    u += 0x7fffu + ((u >> 16) & 1u);
    return (unsigned short)(u >> 16);
}

__device__ __forceinline__ ushort4 pack4(float4 f) {
    ushort4 p;
    p.x = f2bf(f.x); p.y = f2bf(f.y); p.z = f2bf(f.z); p.w = f2bf(f.w);
    return p;
}

__device__ __forceinline__ float fast_tanh(float x) {
    float e = __expf(2.0f * x);
    return 1.0f - 2.0f / (e + 1.0f);
}

// async global->LDS DMA, 16 B per lane (dest must be wave-uniform base + lane*16)
__device__ __forceinline__ void async_copy16(const void* g, void* l) {
    __builtin_amdgcn_global_load_lds(
        (__attribute__((address_space(1))) const void*)g,
        (__attribute__((address_space(3))) void*)l, 16, 0, 0);
}

// ---------------- kernel 1: spb[b][h] = output[b]·W_s[h] + b_attn[h] ----------------
__global__ __launch_bounds__(256)
void spb_kernel(const float* __restrict__ out_state,
                const float* __restrict__ W,
                const float* __restrict__ bias,
                float* __restrict__ spb) {
    int wave = threadIdx.x >> 6, lane = threadIdx.x & 63;
    int g = blockIdx.x * 4 + wave;       // 16384 (b,h) pairs
    int b = g >> 9, h = g & 511;
    const float* wr = W + (size_t)h * 1536;      // W_s row h
    const float* ov = out_state + b * HH;
    float4 w0 = *(const float4*)(wr + lane * 8);
    float4 w1 = *(const float4*)(wr + lane * 8 + 4);
    float4 o0 = *(const float4*)(ov + lane * 8);
    float4 o1 = *(const float4*)(ov + lane * 8 + 4);
    float d = w0.x * o0.x + w0.y * o0.y + w0.z * o0.z + w0.w * o0.w
            + w1.x * o1.x + w1.y * o1.y + w1.z * o1.z + w1.w * o1.w;
    d += __shfl_xor(d, 1); d += __shfl_xor(d, 2); d += __shfl_xor(d, 4);
    d += __shfl_xor(d, 8); d += __shfl_xor(d, 16); d += __shfl_xor(d, 32);
    if (lane == 0) spb[g] = d + bias[h];
}

// ------- kernel 2: W_e -> bf16, FRAG-MAJOR layout Wt[kt][g][lane][8] -------
// g = h>>4, lane = (q<<4)|(h&15), q = (k>>3)&3: a wave's B-frag read is
// 64 lanes x 16B contiguous. One kt tile = 32 KB (K=32 x all 512 h).
__global__ void wconv_kernel(const float* __restrict__ W, unsigned short* __restrict__ Wt) {
    int idx = blockIdx.x * 256 + threadIdx.x;   // 65536 threads, 8 elems each
    int e8 = idx * 8;
    int h = e8 >> 10;        // [0,512)
    int k = e8 & 1023;       // multiple of 8
    const float* src = W + (size_t)h * 1536 + 512 + k;
    float4 w0 = *(const float4*)src;
    float4 w1 = *(const float4*)(src + 4);
    int kt = k >> 5;
    int q  = (k >> 3) & 3;
    int g  = h >> 4;
    int r  = h & 15;
    int ln = (q << 4) | r;
    unsigned short* dst = Wt + (size_t)kt * 16384 + g * 512 + ln * 8;
    *(ushort4*)dst = pack4(w0);
    *(ushort4*)(dst + 4) = pack4(w1);
}

// ---------------- kernel 3: fused GEMM + tanh + v-dot -> scores[b][s] ----------------
// v2: BK=32 periods, dbuf LDS for BOTH operands.
//   B: 32-KB frag-major Wt K-tile staged verbatim via global_load_lds (async,
//      zero VGPR) -> MFMA waits only lgkmcnt, never a vmem counter. This breaks
//      the vmcnt-FIFO coupling that drained the HBM A-prefetch every sub-tile.
//   A: reg-staged fp32->bf16 (produce-side, converted once), 16B-unit XOR
//      swizzle (2-way bank alias = free) since the frag read is 64B-stride rows.
// Regs ~112 (acc 64 + af 16 + bf 16 + f 4 + addr) -> safely under the
// 128-VGPR cap of __launch_bounds__(512,4); 75.8 KB LDS -> 2 blocks/CU.
__global__ __launch_bounds__(512, 4)
void attn_gemm(const float* __restrict__ enc, const unsigned short* __restrict__ Wt,
               const float* __restrict__ spb, const float* __restrict__ vvec,
               float* __restrict__ scores) {
    __shared__ __align__(16) unsigned short Asm[2][2048];   // 64 rows x 32 k bf16, swizzled
    __shared__ __align__(16) unsigned short Bsm[2][16384];  // verbatim Wt K-tile image
    __shared__ float red[8][64];

    const int tid = threadIdx.x;
    const int w = tid >> 6;
    const int lane = tid & 63;
    const int r = lane & 15;
    const int q = lane >> 4;
    const int b = blockIdx.x >> 5;
    const int s0 = (blockIdx.x & 31) << 6;

    // A staging: thread t -> row = t>>3, float4 at k-offset (t&7)*4 in the 32-slab
    const int arow = tid >> 3;
    const int akq  = tid & 7;
    const float* asrc = enc + ((size_t)(b * SS + s0 + arow)) * KK + akq * 4;
    // swizzle: 4x16B units per 64B row; unit' = unit ^ key(row), key = (row^(row>>2))&3
    const int akey = (arow ^ (arow >> 2)) & 3;
    const int ast  = arow * 32 + ((((akq >> 1) ^ akey) << 3) | ((akq & 1) << 2)); // ushorts

    // B staging: 4 x 16B per thread, dest linear (= wave-uniform base + lane*16)
    const unsigned short* bsrc = Wt + tid * 8;

    // fragment read offsets (ushorts)
    const int rkey = (r ^ (r >> 2)) & 3;            // mt*16 doesn't change the key
    const int ard  = r * 32 + ((q ^ rkey) << 3);    // + mt*512
    const int brd  = (w * 4) * 512 + lane * 8;      // + nf*512

    f32x4 acc[4][4] = {};

    // preamble: stage tile 0 into buf 0
    {
        float4 f0 = *(const float4*)asrc;
        #pragma unroll
        for (int c = 0; c < 4; ++c)
            async_copy16(bsrc + c * 4096, &Bsm[0][c * 4096 + tid * 8]);
        *(ushort4*)&Asm[0][ast] = pack4(f0);
    }
    __syncthreads();

    for (int p = 0; p < 32; ++p) {
        const int buf = p & 1;
        float4 f;
        if (p < 31) {
            // issue next tile's A load (HBM) first, then B DMA (L2): pack's wait
            // can then be a counted vmcnt, and the only full drain is the barrier.
            f = *(const float4*)(asrc + (p + 1) * 32);
            const unsigned short* src = bsrc + (size_t)(p + 1) * 16384;
            #pragma unroll
            for (int c = 0; c < 4; ++c)
                async_copy16(src + c * 4096, &Bsm[buf ^ 1][c * 4096 + tid * 8]);
        }
        short8 af[4], bf[4];
        #pragma unroll
        for (int mt = 0; mt < 4; ++mt)
            af[mt] = *(const short8*)&Asm[buf][mt * 512 + ard];
        #pragma unroll
        for (int nf = 0; nf < 4; ++nf)
            bf[nf] = *(const short8*)&Bsm[buf][nf * 512 + brd];
        #pragma unroll
        for (int mt = 0; mt < 4; ++mt)
            #pragma unroll
            for (int nf = 0; nf < 4; ++nf)
                acc[mt][nf] = __builtin_amdgcn_mfma_f32_16x16x32_bf16(
                    af[mt], bf[nf], acc[mt][nf], 0, 0, 0);
        if (p < 31)
            *(ushort4*)&Asm[buf ^ 1][ast] = pack4(f);
        __syncthreads();
    }

    // ---- epilogue: partial score = sum over this wave's 64 cols of v[h]*tanh(.+spb)
    float vh[4], sh[4];
    #pragma unroll
    for (int nf = 0; nf < 4; ++nf) {
        int h = w * 64 + nf * 16 + r;
        vh[nf] = vvec[h];
        sh[nf] = spb[b * HH + h];
    }
    float rowacc[4][4] = {};
    #pragma unroll
    for (int mt = 0; mt < 4; ++mt)
        #pragma unroll
        for (int nf = 0; nf < 4; ++nf)
            #pragma unroll
            for (int i = 0; i < 4; ++i) {
                float x = acc[mt][nf][i] + sh[nf];
                rowacc[mt][i] += vh[nf] * fast_tanh(x);
            }
    #pragma unroll
    for (int mt = 0; mt < 4; ++mt)
        #pragma unroll
        for (int i = 0; i < 4; ++i) {
            float t = rowacc[mt][i];
            t += __shfl_xor(t, 1);
            t += __shfl_xor(t, 2);
            t += __shfl_xor(t, 4);
            t += __shfl_xor(t, 8);
            rowacc[mt][i] = t;
        }
    if (r == 0) {
        #pragma unroll
        for (int mt = 0; mt < 4; ++mt)
            #pragma unroll
            for (int i = 0; i < 4; ++i)
                red[w][mt * 16 + q * 4 + i] = rowacc[mt][i];  // row = mt*16+q*4+i
    }
    __syncthreads();
    if (tid < 64) {
        float sum = 0.f;
        #pragma unroll
        for (int ww = 0; ww < 8; ++ww) sum += red[ww][tid];
        scores[b * SS + s0 + tid] = sum;
    }
}

// ---------------- kernel 4: masked softmax over S per batch ----------------
__global__ void softmax_kernel(const float* __restrict__ scores,
                               const int* __restrict__ mask,
                               float* __restrict__ out) {
    __shared__ float red[256];
    int b = blockIdx.x, tid = threadIdx.x;
    float x[8];
    #pragma unroll
    for (int i = 0; i < 8; ++i) {
        int s = tid + i * 256;
        float sc = scores[b * SS + s];
        if (mask[b * SS + s] == 0) sc -= 1000.0f;
        x[i] = sc;
    }
    float mx = x[0];
    #pragma unroll
    for (int i = 1; i < 8; ++i) mx = fmaxf(mx, x[i]);
    red[tid] = mx;
    __syncthreads();
    for (int o = 128; o > 0; o >>= 1) {
        if (tid < o) red[tid] = fmaxf(red[tid], red[tid + o]);
        __syncthreads();
    }
    mx = red[0];
    __syncthreads();
    float e[8], sum = 0.f;
    #pragma unroll
    for (int i = 0; i < 8; ++i) { e[i] = __expf(x[i] - mx); sum += e[i]; }
    red[tid] = sum;
    __syncthreads();
    for (int o = 128; o > 0; o >>= 1) {
        if (tid < o) red[tid] += red[tid + o];
        __syncthreads();
    }
    float inv = 1.0f / red[0];
    #pragma unroll
    for (int i = 0; i < 8; ++i) out[b * SS + tid + i * 256] = e[i] * inv;
}

extern "C" void kernel_launch(void* const* d_in, const int* in_sizes, int n_in,
                              void* d_out, int out_size, void* d_ws, size_t ws_size,
                              hipStream_t stream) {
    const float* out_state = (const float*)d_in[0];   // (32, 512)
    const float* enc       = (const float*)d_in[1];   // (32, 2048, 1024)
    const int*   mask      = (const int*)d_in[2];     // (32, 2048)
    const float* W_attn    = (const float*)d_in[3];   // (512, 1536)
    const float* b_attn    = (const float*)d_in[4];   // (512,)
    const float* vvec      = (const float*)d_in[5];   // (512,)
    float* out = (float*)d_out;                       // (32, 1, 2048)

    char* ws = (char*)d_ws;
    float*          spb    = (float*)ws;                         // 64 KB
    unsigned short* Wt     = (unsigned short*)(ws + 65536);      // 1 MB
    float*          scores = (float*)(ws + 65536 + 1048576);     // 256 KB

    spb_kernel<<<4096, 256, 0, stream>>>(out_state, W_attn, b_attn, spb);
    wconv_kernel<<<256, 256, 0, stream>>>(W_attn, Wt);
    attn_gemm<<<1024, 512, 0, stream>>>(enc, Wt, spb, vvec, scores);
    softmax_kernel<<<32, 256, 0, stream>>>(scores, mask, out);
}

// Round 2
// 432.114 us; speedup vs baseline: 1.0312x; 1.0312x over previous
//
#include <hip/hip_runtime.h>
#include <hip/hip_bf16.h>

typedef __attribute__((ext_vector_type(4))) float f32x4;
typedef __attribute__((ext_vector_type(8))) short short8;

#define HH 512
#define BB 32
#define SS 2048
#define KK 1024  // 2H

__device__ __forceinline__ unsigned short f2bf(float f) {
    unsigned int u = __float_as_uint(f);
    u += 0x7fffu + ((u >> 16) & 1u);
    return (unsigned short)(u >> 16);
}

__device__ __forceinline__ ushort4 pack4(float4 f) {
    ushort4 p;
    p.x = f2bf(f.x); p.y = f2bf(f.y); p.z = f2bf(f.z); p.w = f2bf(f.w);
    return p;
}

__device__ __forceinline__ float fast_tanh(float x) {
    float e = __expf(2.0f * x);
    return 1.0f - 2.0f / (e + 1.0f);
}

// async global->LDS DMA, 16 B per lane (dest must be wave-uniform base + lane*16)
__device__ __forceinline__ void async_copy16(const void* g, void* l) {
    __builtin_amdgcn_global_load_lds(
        (__attribute__((address_space(1))) const void*)g,
        (__attribute__((address_space(3))) void*)l, 16, 0, 0);
}

// ---------------- kernel 1: spb[b][h] = output[b]·W_s[h] + b_attn[h] ----------------
__global__ __launch_bounds__(256)
void spb_kernel(const float* __restrict__ out_state,
                const float* __restrict__ W,
                const float* __restrict__ bias,
                float* __restrict__ spb) {
    int wave = threadIdx.x >> 6, lane = threadIdx.x & 63;
    int g = blockIdx.x * 4 + wave;       // 16384 (b,h) pairs
    int b = g >> 9, h = g & 511;
    const float* wr = W + (size_t)h * 1536;      // W_s row h
    const float* ov = out_state + b * HH;
    float4 w0 = *(const float4*)(wr + lane * 8);
    float4 w1 = *(const float4*)(wr + lane * 8 + 4);
    float4 o0 = *(const float4*)(ov + lane * 8);
    float4 o1 = *(const float4*)(ov + lane * 8 + 4);
    float d = w0.x * o0.x + w0.y * o0.y + w0.z * o0.z + w0.w * o0.w
            + w1.x * o1.x + w1.y * o1.y + w1.z * o1.z + w1.w * o1.w;
    d += __shfl_xor(d, 1); d += __shfl_xor(d, 2); d += __shfl_xor(d, 4);
    d += __shfl_xor(d, 8); d += __shfl_xor(d, 16); d += __shfl_xor(d, 32);
    if (lane == 0) spb[g] = d + bias[h];
}

// ------- kernel 2: W_e -> bf16, FRAG-MAJOR layout Wt[kt][g][lane][8] -------
// g = h>>4, lane = (q<<4)|(h&15), q = (k>>3)&3: a wave's B-frag read is
// 64 lanes x 16B contiguous. One kt tile = 32 KB (K=32 x all 512 h).
__global__ void wconv_kernel(const float* __restrict__ W, unsigned short* __restrict__ Wt) {
    int idx = blockIdx.x * 256 + threadIdx.x;   // 65536 threads, 8 elems each
    int e8 = idx * 8;
    int h = e8 >> 10;        // [0,512)
    int k = e8 & 1023;       // multiple of 8
    const float* src = W + (size_t)h * 1536 + 512 + k;
    float4 w0 = *(const float4*)src;
    float4 w1 = *(const float4*)(src + 4);
    int kt = k >> 5;
    int q  = (k >> 3) & 3;
    int g  = h >> 4;
    int r  = h & 15;
    int ln = (q << 4) | r;
    unsigned short* dst = Wt + (size_t)kt * 16384 + g * 512 + ln * 8;
    *(ushort4*)dst = pack4(w0);
    *(ushort4*)(dst + 4) = pack4(w1);
}

// ---------------- kernel 3: fused GEMM + tanh + v-dot -> scores[b][s] ----------------
// v3: T3/T4 counted-vmcnt pipeline. Raw s_barrier in the K-loop; the VMEM queue
// is NEVER drained to 0 in steady state:
//   period p: issue B_{p+1} DMAs (4x global_load_lds, L2) -> fence ->
//             issue A_{p+2} global load (HBM, stays in flight ACROSS the barrier)
//             ds_read frags(buf p) -> 16 MFMA
//             pack A_{p+1} -> ds_write Asm[p+1]   (compiler emits counted vmcnt(5))
//             s_waitcnt vmcnt(1) lgkmcnt(0); s_barrier   // B_{p+1} done for all
//                                                        // waves; A_{p+2} flying
// FIFO safety: compiler memory fences pin {B DMAs} older-than {A load}, so
// vmcnt(1) leaves exactly the A load outstanding. Tail peeled (p=30: vmcnt(0)).
__global__ __launch_bounds__(512, 4)
void attn_gemm(const float* __restrict__ enc, const unsigned short* __restrict__ Wt,
               const float* __restrict__ spb, const float* __restrict__ vvec,
               float* __restrict__ scores) {
    __shared__ __align__(16) unsigned short Asm[2][2048];   // 64 rows x 32 k bf16, swizzled
    __shared__ __align__(16) unsigned short Bsm[2][16384];  // verbatim Wt K-tile image
    __shared__ float red[8][64];

    const int tid = threadIdx.x;
    const int w = tid >> 6;
    const int lane = tid & 63;
    const int r = lane & 15;
    const int q = lane >> 4;
    const int bx = blockIdx.x;
    const int b = bx >> 5;
    const int s0 = (bx & 31) << 6;

    // A staging: thread t -> row = t>>3, float4 at k-offset (t&7)*4 in the 32-slab
    const int arow = tid >> 3;
    const int akq  = tid & 7;
    const float* asrc = enc + ((size_t)(b * SS + s0 + arow)) * KK + akq * 4;
    // swizzle: 4x16B units per 64B row; unit' = unit ^ key(row), key = (row^(row>>2))&3
    const int akey = (arow ^ (arow >> 2)) & 3;
    const int ast  = arow * 32 + ((((akq >> 1) ^ akey) << 3) | ((akq & 1) << 2)); // ushorts

    // B staging: 4 x 16B per thread, dest linear (= wave-uniform base + lane*16)
    const unsigned short* bsrc = Wt + tid * 8;

    // fragment read offsets (ushorts)
    const int rkey = (r ^ (r >> 2)) & 3;            // mt*16 doesn't change the key
    const int ard  = r * 32 + ((q ^ rkey) << 3);    // + mt*512
    const int brd  = (w * 4) * 512 + lane * 8;      // + nf*512

    f32x4 acc[4][4] = {};

    // ---- prologue: B_0 DMAs, A_0 + A_1 loads, stage A_0 ----
    #pragma unroll
    for (int c = 0; c < 4; ++c) {
        int cc = (c + bx) & 3;   // stagger L2 channel order across blocks
        async_copy16(bsrc + cc * 4096, &Bsm[0][cc * 4096 + tid * 8]);
    }
    asm volatile("" ::: "memory");   // keep B_0 older than the A loads in the FIFO
    float4 f0 = *(const float4*)asrc;
    float4 fcur = *(const float4*)(asrc + 32);   // A_1, consumed in period 0
    asm volatile("" ::: "memory");
    *(ushort4*)&Asm[0][ast] = pack4(f0);
    // ensure B_0 + A_0 complete (leave A_1 flying), my ds_write visible
    asm volatile("s_waitcnt vmcnt(1) lgkmcnt(0)" ::: "memory");
    __builtin_amdgcn_s_barrier();

    // ---- steady state: p = 0..29 ----
    for (int p = 0; p < 30; ++p) {
        const int buf = p & 1;
        #pragma unroll
        for (int c = 0; c < 4; ++c) {
            int cc = (c + bx) & 3;
            async_copy16(bsrc + (size_t)(p + 1) * 16384 + cc * 4096,
                         &Bsm[buf ^ 1][cc * 4096 + tid * 8]);
        }
        asm volatile("" ::: "memory");   // B_{p+1} must be older than A_{p+2}
        float4 fnext = *(const float4*)(asrc + (size_t)(p + 2) * 32);
        asm volatile("" ::: "memory");

        short8 af[4], bf[4];
        #pragma unroll
        for (int mt = 0; mt < 4; ++mt)
            af[mt] = *(const short8*)&Asm[buf][mt * 512 + ard];
        #pragma unroll
        for (int nf = 0; nf < 4; ++nf)
            bf[nf] = *(const short8*)&Bsm[buf][nf * 512 + brd];
        #pragma unroll
        for (int mt = 0; mt < 4; ++mt)
            #pragma unroll
            for (int nf = 0; nf < 4; ++nf)
                acc[mt][nf] = __builtin_amdgcn_mfma_f32_16x16x32_bf16(
                    af[mt], bf[nf], acc[mt][nf], 0, 0, 0);

        *(ushort4*)&Asm[buf ^ 1][ast] = pack4(fcur);  // auto-wait: vmcnt(5)
        // B_{p+1} complete for this wave (leave only A_{p+2} flying); write visible
        asm volatile("s_waitcnt vmcnt(1) lgkmcnt(0)" ::: "memory");
        __builtin_amdgcn_s_barrier();
        fcur = fnext;
    }

    // ---- p = 30: last B stage, no new A load ----
    {
        #pragma unroll
        for (int c = 0; c < 4; ++c) {
            int cc = (c + bx) & 3;
            async_copy16(bsrc + (size_t)31 * 16384 + cc * 4096,
                         &Bsm[1][cc * 4096 + tid * 8]);
        }
        asm volatile("" ::: "memory");
        short8 af[4], bf[4];
        #pragma unroll
        for (int mt = 0; mt < 4; ++mt)
            af[mt] = *(const short8*)&Asm[0][mt * 512 + ard];
        #pragma unroll
        for (int nf = 0; nf < 4; ++nf)
            bf[nf] = *(const short8*)&Bsm[0][nf * 512 + brd];
        #pragma unroll
        for (int mt = 0; mt < 4; ++mt)
            #pragma unroll
            for (int nf = 0; nf < 4; ++nf)
                acc[mt][nf] = __builtin_amdgcn_mfma_f32_16x16x32_bf16(
                    af[mt], bf[nf], acc[mt][nf], 0, 0, 0);
        *(ushort4*)&Asm[1][ast] = pack4(fcur);
        asm volatile("s_waitcnt vmcnt(0) lgkmcnt(0)" ::: "memory");
        __builtin_amdgcn_s_barrier();
    }

    // ---- p = 31: compute only ----
    {
        short8 af[4], bf[4];
        #pragma unroll
        for (int mt = 0; mt < 4; ++mt)
            af[mt] = *(const short8*)&Asm[1][mt * 512 + ard];
        #pragma unroll
        for (int nf = 0; nf < 4; ++nf)
            bf[nf] = *(const short8*)&Bsm[1][nf * 512 + brd];
        #pragma unroll
        for (int mt = 0; mt < 4; ++mt)
            #pragma unroll
            for (int nf = 0; nf < 4; ++nf)
                acc[mt][nf] = __builtin_amdgcn_mfma_f32_16x16x32_bf16(
                    af[mt], bf[nf], acc[mt][nf], 0, 0, 0);
    }

    // ---- epilogue: partial score = sum over this wave's 64 cols of v[h]*tanh(.+spb)
    float vh[4], sh[4];
    #pragma unroll
    for (int nf = 0; nf < 4; ++nf) {
        int h = w * 64 + nf * 16 + r;
        vh[nf] = vvec[h];
        sh[nf] = spb[b * HH + h];
    }
    float rowacc[4][4] = {};
    #pragma unroll
    for (int mt = 0; mt < 4; ++mt)
        #pragma unroll
        for (int nf = 0; nf < 4; ++nf)
            #pragma unroll
            for (int i = 0; i < 4; ++i) {
                float x = acc[mt][nf][i] + sh[nf];
                rowacc[mt][i] += vh[nf] * fast_tanh(x);
            }
    #pragma unroll
    for (int mt = 0; mt < 4; ++mt)
        #pragma unroll
        for (int i = 0; i < 4; ++i) {
            float t = rowacc[mt][i];
            t += __shfl_xor(t, 1);
            t += __shfl_xor(t, 2);
            t += __shfl_xor(t, 4);
            t += __shfl_xor(t, 8);
            rowacc[mt][i] = t;
        }
    if (r == 0) {
        #pragma unroll
        for (int mt = 0; mt < 4; ++mt)
            #pragma unroll
            for (int i = 0; i < 4; ++i)
                red[w][mt * 16 + q * 4 + i] = rowacc[mt][i];  // row = mt*16+q*4+i
    }
    __syncthreads();
    if (tid < 64) {
        float sum = 0.f;
        #pragma unroll
        for (int ww = 0; ww < 8; ++ww) sum += red[ww][tid];
        scores[b * SS + s0 + tid] = sum;
    }
}

// ---------------- kernel 4: masked softmax over S per batch ----------------
__global__ void softmax_kernel(const float* __restrict__ scores,
                               const int* __restrict__ mask,
                               float* __restrict__ out) {
    __shared__ float red[256];
    int b = blockIdx.x, tid = threadIdx.x;
    float x[8];
    #pragma unroll
    for (int i = 0; i < 8; ++i) {
        int s = tid + i * 256;
        float sc = scores[b * SS + s];
        if (mask[b * SS + s] == 0) sc -= 1000.0f;
        x[i] = sc;
    }
    float mx = x[0];
    #pragma unroll
    for (int i = 1; i < 8; ++i) mx = fmaxf(mx, x[i]);
    red[tid] = mx;
    __syncthreads();
    for (int o = 128; o > 0; o >>= 1) {
        if (tid < o) red[tid] = fmaxf(red[tid], red[tid + o]);
        __syncthreads();
    }
    mx = red[0];
    __syncthreads();
    float e[8], sum = 0.f;
    #pragma unroll
    for (int i = 0; i < 8; ++i) { e[i] = __expf(x[i] - mx); sum += e[i]; }
    red[tid] = sum;
    __syncthreads();
    for (int o = 128; o > 0; o >>= 1) {
        if (tid < o) red[tid] += red[tid + o];
        __syncthreads();
    }
    float inv = 1.0f / red[0];
    #pragma unroll
    for (int i = 0; i < 8; ++i) out[b * SS + tid + i * 256] = e[i] * inv;
}

extern "C" void kernel_launch(void* const* d_in, const int* in_sizes, int n_in,
                              void* d_out, int out_size, void* d_ws, size_t ws_size,
                              hipStream_t stream) {
    const float* out_state = (const float*)d_in[0];   // (32, 512)
    const float* enc       = (const float*)d_in[1];   // (32, 2048, 1024)
    const int*   mask      = (const int*)d_in[2];     // (32, 2048)
    const float* W_attn    = (const float*)d_in[3];   // (512, 1536)
    const float* b_attn    = (const float*)d_in[4];   // (512,)
    const float* vvec      = (const float*)d_in[5];   // (512,)
    float* out = (float*)d_out;                       // (32, 1, 2048)

    char* ws = (char*)d_ws;
    float*          spb    = (float*)ws;                         // 64 KB
    unsigned short* Wt     = (unsigned short*)(ws + 65536);      // 1 MB
    float*          scores = (float*)(ws + 65536 + 1048576);     // 256 KB

    spb_kernel<<<4096, 256, 0, stream>>>(out_state, W_attn, b_attn, spb);
    wconv_kernel<<<256, 256, 0, stream>>>(W_attn, Wt);
    attn_gemm<<<1024, 512, 0, stream>>>(enc, Wt, spb, vvec, scores);
    softmax_kernel<<<32, 256, 0, stream>>>(scores, mask, out);
}

// Round 4
// 413.123 us; speedup vs baseline: 1.0786x; 1.0460x over previous
//
#include <hip/hip_runtime.h>
#include <hip/hip_bf16.h>

typedef __attribute__((ext_vector_type(4))) float f32x4;
typedef __attribute__((ext_vector_type(8))) short short8;

#define HH 512
#define BB 32
#define SS 2048
#define KK 1024  // 2H

__device__ __forceinline__ unsigned short f2bf(float f) {
    unsigned int u = __float_as_uint(f);
    u += 0x7fffu + ((u >> 16) & 1u);
    return (unsigned short)(u >> 16);
}

__device__ __forceinline__ ushort4 pack4(float4 f) {
    ushort4 p;
    p.x = f2bf(f.x); p.y = f2bf(f.y); p.z = f2bf(f.z); p.w = f2bf(f.w);
    return p;
}

__device__ __forceinline__ float fast_tanh(float x) {
    float e = __expf(2.0f * x);
    return 1.0f - 2.0f / (e + 1.0f);
}

// async global->LDS DMA, 16 B per lane (dest = wave-uniform base + lane*16)
__device__ __forceinline__ void dma16(const float* g, float* l) {
    __builtin_amdgcn_global_load_lds(
        (__attribute__((address_space(1))) const void*)g,
        (__attribute__((address_space(3))) void*)l, 16, 0, 0);
}

#define FENCE() asm volatile("" ::: "memory")

// fp32x8 -> bf16x8 (RNE). Scalar casts: compiler lowers to v_cvt_pk_bf16_f32.
__device__ __forceinline__ short8 cvt_bf8(f32x4 a0, f32x4 a1) {
    short8 o;
    #pragma unroll
    for (int i = 0; i < 4; ++i) {
        union { __hip_bfloat16 h; unsigned short u; } c0, c1;
        c0.h = __float2bfloat16(a0[i]);
        c1.h = __float2bfloat16(a1[i]);
        o[i]     = (short)c0.u;
        o[i + 4] = (short)c1.u;
    }
    return o;
}

// ---------------- kernel 1: spb[b][h] = output[b]·W_s[h] + b_attn[h] ----------------
__global__ __launch_bounds__(256)
void spb_kernel(const float* __restrict__ out_state,
                const float* __restrict__ W,
                const float* __restrict__ bias,
                float* __restrict__ spb) {
    int wave = threadIdx.x >> 6, lane = threadIdx.x & 63;
    int g = blockIdx.x * 4 + wave;       // 16384 (b,h) pairs
    int b = g >> 9, h = g & 511;
    const float* wr = W + (size_t)h * 1536;      // W_s row h
    const float* ov = out_state + b * HH;
    float4 w0 = *(const float4*)(wr + lane * 8);
    float4 w1 = *(const float4*)(wr + lane * 8 + 4);
    float4 o0 = *(const float4*)(ov + lane * 8);
    float4 o1 = *(const float4*)(ov + lane * 8 + 4);
    float d = w0.x * o0.x + w0.y * o0.y + w0.z * o0.z + w0.w * o0.w
            + w1.x * o1.x + w1.y * o1.y + w1.z * o1.z + w1.w * o1.w;
    d += __shfl_xor(d, 1); d += __shfl_xor(d, 2); d += __shfl_xor(d, 4);
    d += __shfl_xor(d, 8); d += __shfl_xor(d, 16); d += __shfl_xor(d, 32);
    if (lane == 0) spb[g] = d + bias[h];
}

// ------- kernel 2: W_e -> bf16, FRAG-MAJOR layout Wt[kt][g][lane][8] -------
// g = h>>4, lane = (q<<4)|(h&15), q = (k>>3)&3: a wave's B-frag read is
// 64 lanes x 16B contiguous. One kt tile = 16384 shorts (K=32 x all 512 h).
__global__ void wconv_kernel(const float* __restrict__ W, unsigned short* __restrict__ Wt) {
    int idx = blockIdx.x * 256 + threadIdx.x;   // 65536 threads, 8 elems each
    int e8 = idx * 8;
    int h = e8 >> 10;        // [0,512)
    int k = e8 & 1023;       // multiple of 8
    const float* src = W + (size_t)h * 1536 + 512 + k;
    float4 w0 = *(const float4*)src;
    float4 w1 = *(const float4*)(src + 4);
    int kt = k >> 5;
    int q  = (k >> 3) & 3;
    int g  = h >> 4;
    int r  = h & 15;
    int ln = (q << 4) | r;
    unsigned short* dst = Wt + (size_t)kt * 16384 + g * 512 + ln * 8;
    *(ushort4*)dst = pack4(w0);
    *(ushort4*)(dst + 4) = pack4(w1);
}

// ---------------- kernel 3: fused GEMM + tanh + v-dot -> scores[b][s] ----------------
// v4b (v4 with corrected DMA addressing): 1 block/CU, M=128 x N=512 tile,
// K in 8 eighths of 128 (dbuf 2x64KB fp32 LDS, 128KB total).
//   A: global_load_lds from PRE-SWIZZLED global source (m173). LDS linear for
//      the DMA, holds XOR-swizzled layout; b128 frag reads are ~2-way (free).
//      LDS[row][u] = global[row][u ^ (row&7)] in 16B units (32 units/row).
//   B: register-prefetched frag-major Wt (L2-resident), double-buffered bfr[2].
//      bf always issued BEFORE same-step A-DMAs -> counted bf-waits (vmcnt~8)
//      never drain fresh A-DMAs; DMAs drain ~2 sub-steps after issue.
//   Barrier: once per eighth, s_waitcnt vmcnt(4) lgkmcnt(0) (A done; next-kt
//      bf frags stay in flight ACROSS the barrier). 8 barriers total.
__global__ __launch_bounds__(512, 2)
void attn_gemm(const float* __restrict__ enc, const unsigned short* __restrict__ Wt,
               const float* __restrict__ spb, const float* __restrict__ vvec,
               float* __restrict__ scores) {
    __shared__ __align__(16) float Asm[2][16384];   // 2 x 64 KB: [128 rows][128 k] fp32

    const int tid = threadIdx.x;
    const int w = tid >> 6;
    const int lane = tid & 63;
    const int r = lane & 15;
    const int q = lane >> 4;
    const int b = blockIdx.x >> 4;          // 32 b x 16 s-tiles
    const int s0 = (blockIdx.x & 15) << 7;  // 128 rows per tile
    const int bS = b * SS + s0;

    // ---- A-DMA addressing: per step, 2 DMAs cover rows {w*4+lhi, w*4+2+lhi} ----
    const int l32 = lane & 31, lhi = lane >> 5;
    const int rowA = w * 4 + lhi;           // DMA 0 rows (lanes 0-31 / 32-63)
    const int rowB = w * 4 + 2 + lhi;       // DMA 1 rows
    // pre-swizzled global source: float offset in row-eighth = ((l32^(row&7))<<2)
    const float* aP0 = enc + (size_t)(bS + rowA) * KK + ((l32 ^ (rowA & 7)) << 2);
    const float* aP1 = enc + (size_t)(bS + rowB) * KK + ((l32 ^ (rowB & 7)) << 2);
    // LDS dest float index (per-lane ptr = wave-uniform base + lane*16B)
    const int ad0 = (w * 4) * 128 + lane * 4;
    const int ad1 = (w * 4 + 2) * 128 + lane * 4;

    // ---- B frags: frag-major Wt, wave w covers col groups g = w*4+nf ----
    const short8* wp = (const short8*)(Wt + (size_t)(w * 4) * 512 + lane * 8);
    // + nf*64 (short8) per frag, + kt*2048 (short8) per K-tile

    // ---- A frag read constants (floats) ----
    const int ark = r & 7;        // row&7 for row = mt*16+r
    const int qb = q * 2;         // 16B-unit index base within k32 block
    const int arf = r * 128;      // + mt*2048 per mt

    f32x4 acc[8][4] = {};
    short8 bfr[2][4];

    // ======== prologue: burst-stage eighth 0 (8 DMAs = 64KB/CU in flight) ========
    #pragma unroll
    for (int s = 0; s < 4; ++s) {
        dma16(aP0 + (size_t)s * 32 * KK, &Asm[0][s * 32 * 128 + ad0]);
        dma16(aP1 + (size_t)s * 32 * KK, &Asm[0][s * 32 * 128 + ad1]);
    }
    FENCE();
    #pragma unroll
    for (int nf = 0; nf < 4; ++nf) bfr[0][nf] = wp[nf * 64];   // kt=0
    FENCE();
    asm volatile("s_waitcnt vmcnt(4) lgkmcnt(0)" ::: "memory");  // DMAs done, bf flying
    __builtin_amdgcn_s_barrier();
    __builtin_amdgcn_sched_barrier(0);

    // ======== main: eighths 0..6 (compute e from buf e&1, stage e+1 into other) ========
    for (int e = 0; e < 7; ++e) {
        const float* abase = &Asm[e & 1][0];
        float* sdst = &Asm[(e & 1) ^ 1][0];
        const size_t koff = (size_t)(e + 1) * 128;   // k offset of eighth e+1
        #pragma unroll
        for (int s = 0; s < 4; ++s) {
            const int ktn = e * 4 + s + 1;           // next kt to prefetch
            if (s < 3) {
                #pragma unroll
                for (int nf = 0; nf < 4; ++nf)
                    bfr[(s + 1) & 1][nf] = wp[(size_t)ktn * 2048 + nf * 64];
                FENCE();
                dma16(aP0 + koff + (size_t)s * 32 * KK, sdst + s * 32 * 128 + ad0);
                dma16(aP1 + koff + (size_t)s * 32 * KK, sdst + s * 32 * 128 + ad1);
                FENCE();
            } else {
                // last sub-step: DMAs BEFORE bf so vmcnt(4) at the barrier leaves
                // exactly the 4 next-kt bf loads in flight.
                dma16(aP0 + koff + (size_t)3 * 32 * KK, sdst + 3 * 32 * 128 + ad0);
                dma16(aP1 + koff + (size_t)3 * 32 * KK, sdst + 3 * 32 * 128 + ad1);
                FENCE();
                #pragma unroll
                for (int nf = 0; nf < 4; ++nf)
                    bfr[0][nf] = wp[(size_t)ktn * 2048 + nf * 64];
                FENCE();
            }
            const int u0 = ((s * 8 + qb) ^ ark) << 2;
            const int u1 = ((s * 8 + qb + 1) ^ ark) << 2;
            #pragma unroll
            for (int mt = 0; mt < 8; ++mt) {
                const int rowf = mt * 2048 + arf;
                f32x4 a0 = *(const f32x4*)(abase + rowf + u0);
                f32x4 a1 = *(const f32x4*)(abase + rowf + u1);
                short8 af = cvt_bf8(a0, a1);
                #pragma unroll
                for (int nf = 0; nf < 4; ++nf)
                    acc[mt][nf] = __builtin_amdgcn_mfma_f32_16x16x32_bf16(
                        af, bfr[s & 1][nf], acc[mt][nf], 0, 0, 0);
            }
        }
        asm volatile("s_waitcnt vmcnt(4) lgkmcnt(0)" ::: "memory");
        __builtin_amdgcn_s_barrier();
        __builtin_amdgcn_sched_barrier(0);
    }

    // ======== peeled eighth 7: compute only (from buf 1) ========
    {
        const float* abase = &Asm[1][0];
        #pragma unroll
        for (int s = 0; s < 4; ++s) {
            if (s < 3) {
                const int ktn = 29 + s;
                #pragma unroll
                for (int nf = 0; nf < 4; ++nf)
                    bfr[(s + 1) & 1][nf] = wp[(size_t)ktn * 2048 + nf * 64];
                FENCE();
            }
            const int u0 = ((s * 8 + qb) ^ ark) << 2;
            const int u1 = ((s * 8 + qb + 1) ^ ark) << 2;
            #pragma unroll
            for (int mt = 0; mt < 8; ++mt) {
                const int rowf = mt * 2048 + arf;
                f32x4 a0 = *(const f32x4*)(abase + rowf + u0);
                f32x4 a1 = *(const f32x4*)(abase + rowf + u1);
                short8 af = cvt_bf8(a0, a1);
                #pragma unroll
                for (int nf = 0; nf < 4; ++nf)
                    acc[mt][nf] = __builtin_amdgcn_mfma_f32_16x16x32_bf16(
                        af, bfr[s & 1][nf], acc[mt][nf], 0, 0, 0);
            }
        }
    }

    // ---- epilogue: partial score = sum over this wave's 64 cols of v[h]*tanh(.+spb)
    // red aliases Asm[0]: last Asm[0] reads were eighth 6, sealed by its barrier.
    float* red = (float*)&Asm[0][0];   // [8][128]
    float vh[4], sh[4];
    #pragma unroll
    for (int nf = 0; nf < 4; ++nf) {
        int h = w * 64 + nf * 16 + r;
        vh[nf] = vvec[h];
        sh[nf] = spb[b * HH + h];
    }
    float rowacc[8][4] = {};
    #pragma unroll
    for (int mt = 0; mt < 8; ++mt)
        #pragma unroll
        for (int nf = 0; nf < 4; ++nf)
            #pragma unroll
            for (int i = 0; i < 4; ++i) {
                float x = acc[mt][nf][i] + sh[nf];
                rowacc[mt][i] += vh[nf] * fast_tanh(x);
            }
    #pragma unroll
    for (int mt = 0; mt < 8; ++mt)
        #pragma unroll
        for (int i = 0; i < 4; ++i) {
            float t = rowacc[mt][i];
            t += __shfl_xor(t, 1);
            t += __shfl_xor(t, 2);
            t += __shfl_xor(t, 4);
            t += __shfl_xor(t, 8);
            rowacc[mt][i] = t;
        }
    if (r == 0) {
        #pragma unroll
        for (int mt = 0; mt < 8; ++mt)
            #pragma unroll
            for (int i = 0; i < 4; ++i)
                red[w * 128 + mt * 16 + q * 4 + i] = rowacc[mt][i];
    }
    __syncthreads();
    if (tid < 128) {
        float sum = 0.f;
        #pragma unroll
        for (int ww = 0; ww < 8; ++ww) sum += red[ww * 128 + tid];
        scores[bS + tid] = sum;
    }
}

// ---------------- kernel 4: masked softmax over S per batch ----------------
__global__ void softmax_kernel(const float* __restrict__ scores,
                               const int* __restrict__ mask,
                               float* __restrict__ out) {
    __shared__ float red[256];
    int b = blockIdx.x, tid = threadIdx.x;
    float x[8];
    #pragma unroll
    for (int i = 0; i < 8; ++i) {
        int s = tid + i * 256;
        float sc = scores[b * SS + s];
        if (mask[b * SS + s] == 0) sc -= 1000.0f;
        x[i] = sc;
    }
    float mx = x[0];
    #pragma unroll
    for (int i = 1; i < 8; ++i) mx = fmaxf(mx, x[i]);
    red[tid] = mx;
    __syncthreads();
    for (int o = 128; o > 0; o >>= 1) {
        if (tid < o) red[tid] = fmaxf(red[tid], red[tid + o]);
        __syncthreads();
    }
    mx = red[0];
    __syncthreads();
    float e[8], sum = 0.f;
    #pragma unroll
    for (int i = 0; i < 8; ++i) { e[i] = __expf(x[i] - mx); sum += e[i]; }
    red[tid] = sum;
    __syncthreads();
    for (int o = 128; o > 0; o >>= 1) {
        if (tid < o) red[tid] += red[tid + o];
        __syncthreads();
    }
    float inv = 1.0f / red[0];
    #pragma unroll
    for (int i = 0; i < 8; ++i) out[b * SS + tid + i * 256] = e[i] * inv;
}

extern "C" void kernel_launch(void* const* d_in, const int* in_sizes, int n_in,
                              void* d_out, int out_size, void* d_ws, size_t ws_size,
                              hipStream_t stream) {
    const float* out_state = (const float*)d_in[0];   // (32, 512)
    const float* enc       = (const float*)d_in[1];   // (32, 2048, 1024)
    const int*   mask      = (const int*)d_in[2];     // (32, 2048)
    const float* W_attn    = (const float*)d_in[3];   // (512, 1536)
    const float* b_attn    = (const float*)d_in[4];   // (512,)
    const float* vvec      = (const float*)d_in[5];   // (512,)
    float* out = (float*)d_out;                       // (32, 1, 2048)

    char* ws = (char*)d_ws;
    float*          spb    = (float*)ws;                         // 64 KB
    unsigned short* Wt     = (unsigned short*)(ws + 65536);      // 1 MB
    float*          scores = (float*)(ws + 65536 + 1048576);     // 256 KB

    spb_kernel<<<4096, 256, 0, stream>>>(out_state, W_attn, b_attn, spb);
    wconv_kernel<<<256, 256, 0, stream>>>(W_attn, Wt);
    attn_gemm<<<512, 512, 0, stream>>>(enc, Wt, spb, vvec, scores);
    softmax_kernel<<<32, 256, 0, stream>>>(scores, mask, out);
}